// Round 16
// baseline (80.807 us; speedup 1.0000x reference)
//
#include <hip/hip_runtime.h>
#include <hip/hip_bf16.h>
#include <float.h>

#define DIMS 64
#define KC 1024
#define M_TOTAL 65536
#define TAU 4e-3f   // split-bf16 dist err ~1.5e-4 std (proven r3-r15)

typedef __attribute__((ext_vector_type(8))) short bf16x8;   // 8 bf16 = 4 VGPRs
typedef __attribute__((ext_vector_type(4))) float f32x4;

// ---------------- ws layout (float elements), 528384 f = 2.1 MB -------------
#define SE_OFF   0            // 1024 f32 codebook sq norms
#define CTL_OFF  1024         // [0]=refine cnt
#define PART_OFF 2048         // 1024 f32 loss partials
#define PBH_OFF  4096         // 32768 f32: bf16 hi frags (16x16x32 layout)
#define PBL_OFF  36864        // 32768 f32: bf16 lo frags
#define M1_OFF   69632        // 2*65536 per-split min1
#define M2_OFF   200704       // 2*65536 per-split min2
#define IDX_OFF  331776       // 2*65536 per-split argmin; merged -> first half
#define WL_OFF   462848       // 65536 int worklist

__device__ inline short f2bf(float x) {
  union { __hip_bfloat16 h; short s; } u;
  u.h = __float2bfloat16(x);
  return u.s;
}
__device__ inline float bf2f(short x) {
  union { short s; __hip_bfloat16 h; } u;
  u.s = x;
  return __bfloat162float(u.h);
}

// async global->LDS, 16B per lane; lds dest wave-uniform (HW writes dest + lane*16)
__device__ inline void gload_lds16(const void* g, void* l) {
  __builtin_amdgcn_global_load_lds(
      (const __attribute__((address_space(1))) void*)g,
      (__attribute__((address_space(3))) void*)l, 16, 0, 0);
}

// fused: pack codebook into bf16 MFMA B-fragment layout (hi + lo residue) + sq norms + zero ctl
// frag[((tile*2 + ks)*64 + lane)*8 + j] = E[16*tile + (lane&15)][32*ks + (lane>>4)*8 + j]
__global__ __launch_bounds__(256) void k_prep(const float* __restrict__ cb,
                                              float* __restrict__ se,
                                              unsigned int* __restrict__ ctl,
                                              unsigned short* __restrict__ pbh,
                                              unsigned short* __restrict__ pbl) {
  const int tid = blockIdx.x * 256 + threadIdx.x;  // 8192 total
  if (tid < 4) ctl[tid] = 0;
  const int l = tid & 63;
  const int s = (tid >> 6) & 1;
  const int tt = tid >> 7;
  const int code = tt * 16 + (l & 15);
  const int k = s * 32 + (l >> 4) * 8;
  const float* p = cb + (size_t)code * DIMS + k;
  float v[8];
  ((float4*)v)[0] = ((const float4*)p)[0];
  ((float4*)v)[1] = ((const float4*)p)[1];
  bf16x8 h, lo;
#pragma unroll
  for (int j = 0; j < 8; ++j) {
    short hj = f2bf(v[j]);
    h[j] = hj;
    lo[j] = f2bf(v[j] - bf2f(hj));
  }
  *(bf16x8*)(pbh + (size_t)tid * 8) = h;
  *(bf16x8*)(pbl + (size_t)tid * 8) = lo;

  if (tid < KC) {
    const float4* q = (const float4*)(cb + (size_t)tid * DIMS);
    float a0 = 0.f, a1 = 0.f, a2 = 0.f, a3 = 0.f;
#pragma unroll
    for (int i = 0; i < DIMS / 4; ++i) {
      float4 u = q[i];
      a0 = fmaf(u.x, u.x, a0);
      a1 = fmaf(u.y, u.y, a1);
      a2 = fmaf(u.z, u.z, a2);
      a3 = fmaf(u.w, u.w, a3);
    }
    se[tid] = (a0 + a1) + (a2 + a3);
  }
}

// MFMA phase-1 (split bf16): R14's proven kernel, 2-way code split for occupancy.
// wave = 16 rows x 512 codes; block = 4 waves; grid 2048 -> 8 blocks/CU = 32 waves/CU.
// R5 schedule: stage(c+1) at top, MFMAs on chunk c, sync at bottom; sec = per-tile
// GLOBAL load consumed only in the epilogue.
// C/D layout (m89-verified): col = lane&15, row = (lane>>4)*4 + reg.
__global__ __launch_bounds__(256, 8) void k_dist(const float* __restrict__ z,
                                                 const unsigned short* __restrict__ pbh,
                                                 const unsigned short* __restrict__ pbl,
                                                 const float* __restrict__ se,
                                                 float* __restrict__ m1o,
                                                 float* __restrict__ m2o,
                                                 int* __restrict__ idxo) {
  __shared__ bf16x8 sB[2][2][256];  // [buf][hi/lo][frag] = 16 KB
  const int l = threadIdx.x & 63;
  const int w = threadIdx.x >> 6;
  const int split = blockIdx.x & 1;
  const int rb = blockIdx.x >> 1;
  const int r0 = rb * 64 + w * 16;
  const int col = l & 15;
  const int g = l >> 4;

  // A fragments (hi + lo residue), 2 ksteps of 32
  bf16x8 ah[2], al[2];
  {
    const float* zp = z + (size_t)(r0 + col) * DIMS + g * 8;
#pragma unroll
    for (int ks = 0; ks < 2; ++ks) {
      float v[8];
      ((float4*)v)[0] = ((const float4*)(zp + ks * 32))[0];
      ((float4*)v)[1] = ((const float4*)(zp + ks * 32))[1];
#pragma unroll
      for (int j = 0; j < 8; ++j) {
        short hj = f2bf(v[j]);
        ah[ks][j] = hj;
        al[ks][j] = f2bf(v[j] - bf2f(hj));
      }
    }
  }

  float m1[4] = {FLT_MAX, FLT_MAX, FLT_MAX, FLT_MAX};
  float m2[4] = {FLT_MAX, FLT_MAX, FLT_MAX, FLT_MAX};
  int bt[4] = {0, 0, 0, 0};

  const int C0 = split * 16;  // 16 chunks of 32 codes per split
  // stage chunk 0 (8 KB: 256 hi frags + 256 lo frags; 2 gload_lds per thread)
  {
    const size_t f = (size_t)C0 * 256 + w * 64 + l;
    gload_lds16(pbh + f * 8, &sB[0][0][w * 64]);
    gload_lds16(pbl + f * 8, &sB[0][1][w * 64]);
  }
  __syncthreads();

  int cur = 0;
  for (int c = 0; c < 16; ++c) {           // 16 chunks x 32 codes
    if (c + 1 < 16) {
      const size_t f = (size_t)(C0 + c + 1) * 256 + w * 64 + l;
      gload_lds16(pbh + f * 8, &sB[cur ^ 1][0][w * 64]);
      gload_lds16(pbl + f * 8, &sB[cur ^ 1][1][w * 64]);
    }
#pragma unroll
    for (int tt = 0; tt < 2; ++tt) {       // 2 tiles of 16 codes
      const int t = (C0 + c) * 2 + tt;     // global 16-code tile index [0,64)
      bf16x8 bh0 = sB[cur][0][tt * 128 + l];
      bf16x8 bh1 = sB[cur][0][tt * 128 + 64 + l];
      bf16x8 bl0 = sB[cur][1][tt * 128 + l];
      bf16x8 bl1 = sB[cur][1][tt * 128 + 64 + l];
      const float sec = se[t * 16 + col];  // global, epilogue-only use
      f32x4 acc = {0.f, 0.f, 0.f, 0.f};
      acc = __builtin_amdgcn_mfma_f32_16x16x32_bf16(ah[0], bh0, acc, 0, 0, 0);
      acc = __builtin_amdgcn_mfma_f32_16x16x32_bf16(ah[1], bh1, acc, 0, 0, 0);
      acc = __builtin_amdgcn_mfma_f32_16x16x32_bf16(ah[0], bl0, acc, 0, 0, 0);
      acc = __builtin_amdgcn_mfma_f32_16x16x32_bf16(ah[1], bl1, acc, 0, 0, 0);
      acc = __builtin_amdgcn_mfma_f32_16x16x32_bf16(al[0], bh0, acc, 0, 0, 0);
      acc = __builtin_amdgcn_mfma_f32_16x16x32_bf16(al[1], bh1, acc, 0, 0, 0);
#pragma unroll
      for (int j = 0; j < 4; ++j) {
        float d = fmaf(-2.f, acc[j], sec);
        float nm2 = __builtin_amdgcn_fmed3f(d, m1[j], m2[j]);  // new 2nd-min
        bool lt = d < m1[j];
        m1[j] = lt ? d : m1[j];
        bt[j] = lt ? t : bt[j];
        m2[j] = nm2;
      }
    }
    __syncthreads();
    cur ^= 1;
  }

  // cross-lane reduce over the 16 cols of each row group; lowest-index tie-break
#pragma unroll
  for (int j = 0; j < 4; ++j) {
    float m1j = m1[j], m2j = m2[j];
    int ij = bt[j] * 16 + col;  // global code index (t was global)
    for (int msk = 1; msk <= 8; msk <<= 1) {
      float o1 = __shfl_xor(m1j, msk);
      float o2 = __shfl_xor(m2j, msk);
      int oi = __shfl_xor(ij, msk);
      bool take = (o1 < m1j) || (o1 == m1j && oi < ij);
      float hi = take ? m1j : o1;  // losing min1 becomes min2 candidate
      m2j = fminf(fminf(m2j, o2), hi);
      m1j = take ? o1 : m1j;
      ij = take ? oi : ij;
    }
    if (col == 0) {
      const int o = split * M_TOTAL + r0 + g * 4 + j;
      m1o[o] = m1j;
      m2o[o] = m2j;
      idxo[o] = ij;
    }
  }
}

// merge the two code-splits per row + build refine worklist (R7-proven semantics)
__global__ __launch_bounds__(256) void k_merge(const float* __restrict__ m1s,
                                               const float* __restrict__ m2s,
                                               int* __restrict__ idxs,
                                               int* __restrict__ wl,
                                               unsigned int* __restrict__ ctl) {
  const int row = blockIdx.x * 256 + threadIdx.x;
  const float a1 = m1s[row], b1 = m1s[M_TOTAL + row];
  const float a2 = m2s[row], b2 = m2s[M_TOTAL + row];
  const int ia = idxs[row], ib = idxs[M_TOTAL + row];
  const float m1 = fminf(a1, b1);
  const float m2 = fminf(fmaxf(a1, b1), fminf(a2, b2));
  idxs[row] = (b1 < a1) ? ib : ia;  // tie -> split 0 (lower code index)
  if (m2 - m1 < TAU) {
    int p = atomicAdd((int*)ctl, 1);
    wl[p] = row;
  }
}

// exact fp64 diff-form re-resolution for flagged rows (worklist, ~0.3% of rows)
__global__ __launch_bounds__(256) void k_refine(const float* __restrict__ z,
                                                const float* __restrict__ cb,
                                                const int* __restrict__ wl,
                                                const unsigned int* __restrict__ ctl,
                                                int* __restrict__ idxo) {
  __shared__ float zz[64];
  __shared__ double sd[256];
  __shared__ int si[256];
  const int t = threadIdx.x;
  const int n = (int)ctl[0];
  for (int wi = blockIdx.x; wi < n; wi += 1024) {
    const int row = wl[wi];
    if (t < 16) ((float4*)zz)[t] = ((const float4*)(z + (size_t)row * DIMS))[t];
    __syncthreads();
    const int c0 = t * 4;
    double accd[4] = {0.0, 0.0, 0.0, 0.0};
    for (int ch = 0; ch < 4; ++ch) {
      float zr[16];
#pragma unroll
      for (int q = 0; q < 4; ++q) ((float4*)zr)[q] = ((float4*)zz)[ch * 4 + q];
#pragma unroll
      for (int cc = 0; cc < 4; ++cc) {
        const float* e = cb + (size_t)(c0 + cc) * DIMS + ch * 16;
#pragma unroll
        for (int q = 0; q < 16; ++q) {
          double df = (double)zr[q] - (double)e[q];
          accd[cc] = fma(df, df, accd[cc]);
        }
      }
    }
    double best = 1e300;
    int bi = 0;
#pragma unroll
    for (int cc = 0; cc < 4; ++cc)
      if (accd[cc] < best) { best = accd[cc]; bi = c0 + cc; }
    sd[t] = best;
    si[t] = bi;
    __syncthreads();
    for (int off = 128; off > 0; off >>= 1) {
      if (t < off) {
        double ob = sd[t + off];
        int oi = si[t + off];
        if (ob < sd[t] || (ob == sd[t] && oi < si[t])) { sd[t] = ob; si[t] = oi; }
      }
      __syncthreads();
    }
    if (t == 0) idxo[row] = si[0];
    __syncthreads();
  }
}

// gather + straight-through output (z + (e - z), ref rounding) + loss partials
__global__ __launch_bounds__(256) void k_out(const float* __restrict__ z,
                                             const float* __restrict__ cb,
                                             const int* __restrict__ idxi,
                                             float* __restrict__ out,
                                             float* __restrict__ partials) {
  const int tid = blockIdx.x * 256 + threadIdx.x;  // 262144: quarter-row each
  const int row = tid >> 2;
  const int q = tid & 3;
  const int code = idxi[row];
  const float4* zp = (const float4*)(z + (size_t)row * DIMS + q * 16);
  const float4* ep = (const float4*)(cb + (size_t)code * DIMS + q * 16);
  float4* op = (float4*)(out + (size_t)row * DIMS + q * 16);
  float sse = 0.f;
#pragma unroll
  for (int i = 0; i < 4; ++i) {
    float4 v = zp[i], e = ep[i];
    float dx = e.x - v.x, dy = e.y - v.y, dz = e.z - v.z, dw = e.w - v.w;
    sse = fmaf(dx, dx, sse);
    sse = fmaf(dy, dy, sse);
    sse = fmaf(dz, dz, sse);
    sse = fmaf(dw, dw, sse);
    float4 o;
    o.x = v.x + dx;
    o.y = v.y + dy;
    o.z = v.z + dz;
    o.w = v.w + dw;
    op[i] = o;
  }
  __shared__ float sh[256];
  sh[threadIdx.x] = sse;
  __syncthreads();
  for (int off = 128; off > 0; off >>= 1) {
    if (threadIdx.x < off) sh[threadIdx.x] += sh[threadIdx.x + off];
    __syncthreads();
  }
  if (threadIdx.x == 0) partials[blockIdx.x] = sh[0];
}

__global__ __launch_bounds__(256) void k_loss(const float* __restrict__ partials,
                                              float* __restrict__ out) {
  __shared__ float sh[256];
  const int t = threadIdx.x;
  sh[t] = partials[t] + partials[t + 256] + partials[t + 512] + partials[t + 768];
  __syncthreads();
  for (int off = 128; off > 0; off >>= 1) {
    if (t < off) sh[t] += sh[t + off];
    __syncthreads();
  }
  if (t == 0) {
    // (0.1*mse + mse) * 10 = 11 * SSE / (M*D)
    out[(size_t)M_TOTAL * DIMS] = sh[0] * (11.0f / (float)((size_t)M_TOTAL * DIMS));
  }
}

extern "C" void kernel_launch(void* const* d_in, const int* in_sizes, int n_in,
                              void* d_out, int out_size, void* d_ws, size_t ws_size,
                              hipStream_t stream) {
  const float* z = (const float*)d_in[0];
  const float* cb = (const float*)d_in[1];
  float* out = (float*)d_out;
  float* ws = (float*)d_ws;

  float* se = ws + SE_OFF;
  unsigned int* ctl = (unsigned int*)(ws + CTL_OFF);
  float* partials = ws + PART_OFF;
  unsigned short* pbh = (unsigned short*)(ws + PBH_OFF);
  unsigned short* pbl = (unsigned short*)(ws + PBL_OFF);
  float* m1s = ws + M1_OFF;
  float* m2s = ws + M2_OFF;
  int* idx = (int*)(ws + IDX_OFF);
  int* wl = (int*)(ws + WL_OFF);

  k_prep<<<32, 256, 0, stream>>>(cb, se, ctl, pbh, pbl);
  k_dist<<<(M_TOTAL / 64) * 2, 256, 0, stream>>>(z, pbh, pbl, se, m1s, m2s, idx);
  k_merge<<<M_TOTAL / 256, 256, 0, stream>>>(m1s, m2s, idx, wl, ctl);
  k_refine<<<1024, 256, 0, stream>>>(z, cb, wl, ctl, idx);
  k_out<<<M_TOTAL / 64, 256, 0, stream>>>(z, cb, idx, out, partials);
  k_loss<<<1, 256, 0, stream>>>(partials, out);
}

// Round 17
// 62.600 us; speedup vs baseline: 1.2908x; 1.2908x over previous
//
#include <hip/hip_runtime.h>
#include <hip/hip_bf16.h>
#include <float.h>

#define DIMS 64
#define KC 1024
#define M_TOTAL 65536
#define TAU 4e-3f   // split-bf16 dist err ~1.5e-4 std (proven r3-r16)

typedef __attribute__((ext_vector_type(8))) short bf16x8;   // 8 bf16 = 4 VGPRs
typedef __attribute__((ext_vector_type(4))) float f32x4;

// ---------------- ws layout (float elements), 200704 f = 803 KB -------------
#define SE_OFF   0            // 1024 f32 codebook sq norms
#define CTL_OFF  1024         // [0]=refine cnt
#define PBH_OFF  4096         // 32768 f32: bf16 hi frags
#define PBL_OFF  36864        // 32768 f32: bf16 lo frags
#define WL_OFF   69632        // 65536 int worklist
#define SROW_OFF 135168       // 65536 f32 per-row sse (k_dist writes all; refine fixes)

__device__ inline short f2bf(float x) {
  union { __hip_bfloat16 h; short s; } u;
  u.h = __float2bfloat16(x);
  return u.s;
}
__device__ inline float bf2f(short x) {
  union { short s; __hip_bfloat16 h; } u;
  u.s = x;
  return __bfloat162float(u.h);
}

// async global->LDS, 16B per lane; lds dest wave-uniform (HW writes dest + lane*16)
__device__ inline void gload_lds16(const void* g, void* l) {
  __builtin_amdgcn_global_load_lds(
      (const __attribute__((address_space(1))) void*)g,
      (__attribute__((address_space(3))) void*)l, 16, 0, 0);
}

// fused: pack codebook into bf16 MFMA B-fragment layout (hi + lo residue) + sq norms + zero ctl
// frag[((tile*2 + ks)*64 + lane)*8 + j] = E[16*tile + (lane&15)][32*ks + (lane>>4)*8 + j]
__global__ __launch_bounds__(256) void k_prep(const float* __restrict__ cb,
                                              float* __restrict__ se,
                                              unsigned int* __restrict__ ctl,
                                              unsigned short* __restrict__ pbh,
                                              unsigned short* __restrict__ pbl) {
  const int tid = blockIdx.x * 256 + threadIdx.x;  // 8192 total
  if (tid < 4) ctl[tid] = 0;
  const int l = tid & 63;
  const int s = (tid >> 6) & 1;
  const int tt = tid >> 7;
  const int code = tt * 16 + (l & 15);
  const int k = s * 32 + (l >> 4) * 8;
  const float* p = cb + (size_t)code * DIMS + k;
  float v[8];
  ((float4*)v)[0] = ((const float4*)p)[0];
  ((float4*)v)[1] = ((const float4*)p)[1];
  bf16x8 h, lo;
#pragma unroll
  for (int j = 0; j < 8; ++j) {
    short hj = f2bf(v[j]);
    h[j] = hj;
    lo[j] = f2bf(v[j] - bf2f(hj));
  }
  *(bf16x8*)(pbh + (size_t)tid * 8) = h;
  *(bf16x8*)(pbl + (size_t)tid * 8) = lo;

  if (tid < KC) {
    const float4* q = (const float4*)(cb + (size_t)tid * DIMS);
    float a0 = 0.f, a1 = 0.f, a2 = 0.f, a3 = 0.f;
#pragma unroll
    for (int i = 0; i < DIMS / 4; ++i) {
      float4 u = q[i];
      a0 = fmaf(u.x, u.x, a0);
      a1 = fmaf(u.y, u.y, a1);
      a2 = fmaf(u.z, u.z, a2);
      a3 = fmaf(u.w, u.w, a3);
    }
    se[tid] = (a0 + a1) + (a2 + a3);
  }
}

// MFMA phase-1 (R14's proven 40us kernel) + FUSED output stage.
// wave = 16 rows x 1024 codes; block = 4 waves = 64 rows; grid 1024.
// After argmin: s_idx[64] in LDS -> 256 threads gather cb[idx], write
// out = z + (e - z) (ref rounding) and per-row sse (srow) -- k_out eliminated.
// C/D layout (m89-verified): col = lane&15, row = (lane>>4)*4 + reg.
__global__ __launch_bounds__(256, 4) void k_dist(const float* __restrict__ z,
                                                 const unsigned short* __restrict__ pbh,
                                                 const unsigned short* __restrict__ pbl,
                                                 const float* __restrict__ se,
                                                 const float* __restrict__ cb,
                                                 float* __restrict__ out,
                                                 float* __restrict__ srow,
                                                 int* __restrict__ wl,
                                                 unsigned int* __restrict__ ctl) {
  __shared__ bf16x8 sB[2][2][256];  // [buf][hi/lo][frag] = 16 KB
  __shared__ int s_idx[64];
  const int l = threadIdx.x & 63;
  const int w = threadIdx.x >> 6;
  const int r0 = blockIdx.x * 64 + w * 16;
  const int col = l & 15;
  const int g = l >> 4;

  // A fragments (hi + lo residue), 2 ksteps of 32
  bf16x8 ah[2], al[2];
  {
    const float* zp = z + (size_t)(r0 + col) * DIMS + g * 8;
#pragma unroll
    for (int ks = 0; ks < 2; ++ks) {
      float v[8];
      ((float4*)v)[0] = ((const float4*)(zp + ks * 32))[0];
      ((float4*)v)[1] = ((const float4*)(zp + ks * 32))[1];
#pragma unroll
      for (int j = 0; j < 8; ++j) {
        short hj = f2bf(v[j]);
        ah[ks][j] = hj;
        al[ks][j] = f2bf(v[j] - bf2f(hj));
      }
    }
  }

  float m1[4] = {FLT_MAX, FLT_MAX, FLT_MAX, FLT_MAX};
  float m2[4] = {FLT_MAX, FLT_MAX, FLT_MAX, FLT_MAX};
  int bt[4] = {0, 0, 0, 0};

  // stage chunk 0 (8 KB: 256 hi frags + 256 lo frags; 2 gload_lds per thread)
  {
    const int f = w * 64 + l;
    gload_lds16(pbh + (size_t)f * 8, &sB[0][0][w * 64]);
    gload_lds16(pbl + (size_t)f * 8, &sB[0][1][w * 64]);
  }
  __syncthreads();

  int cur = 0;
  for (int c = 0; c < 32; ++c) {           // 32 chunks x 32 codes
    if (c + 1 < 32) {
      const size_t f = (size_t)(c + 1) * 256 + w * 64 + l;
      gload_lds16(pbh + f * 8, &sB[cur ^ 1][0][w * 64]);
      gload_lds16(pbl + f * 8, &sB[cur ^ 1][1][w * 64]);
    }
#pragma unroll
    for (int tt = 0; tt < 2; ++tt) {       // 2 tiles of 16 codes
      const int t = c * 2 + tt;
      bf16x8 bh0 = sB[cur][0][tt * 128 + l];
      bf16x8 bh1 = sB[cur][0][tt * 128 + 64 + l];
      bf16x8 bl0 = sB[cur][1][tt * 128 + l];
      bf16x8 bl1 = sB[cur][1][tt * 128 + 64 + l];
      const float sec = se[t * 16 + col];  // global, epilogue-only use
      f32x4 acc = {0.f, 0.f, 0.f, 0.f};
      acc = __builtin_amdgcn_mfma_f32_16x16x32_bf16(ah[0], bh0, acc, 0, 0, 0);
      acc = __builtin_amdgcn_mfma_f32_16x16x32_bf16(ah[1], bh1, acc, 0, 0, 0);
      acc = __builtin_amdgcn_mfma_f32_16x16x32_bf16(ah[0], bl0, acc, 0, 0, 0);
      acc = __builtin_amdgcn_mfma_f32_16x16x32_bf16(ah[1], bl1, acc, 0, 0, 0);
      acc = __builtin_amdgcn_mfma_f32_16x16x32_bf16(al[0], bh0, acc, 0, 0, 0);
      acc = __builtin_amdgcn_mfma_f32_16x16x32_bf16(al[1], bh1, acc, 0, 0, 0);
#pragma unroll
      for (int j = 0; j < 4; ++j) {
        float d = fmaf(-2.f, acc[j], sec);
        float nm2 = __builtin_amdgcn_fmed3f(d, m1[j], m2[j]);  // new 2nd-min
        bool lt = d < m1[j];
        m1[j] = lt ? d : m1[j];
        bt[j] = lt ? t : bt[j];
        m2[j] = nm2;
      }
    }
    __syncthreads();
    cur ^= 1;
  }

  // cross-lane reduce over the 16 cols of each row group; lowest-index tie-break
#pragma unroll
  for (int j = 0; j < 4; ++j) {
    float m1j = m1[j], m2j = m2[j];
    int ij = bt[j] * 16 + col;
    for (int msk = 1; msk <= 8; msk <<= 1) {
      float o1 = __shfl_xor(m1j, msk);
      float o2 = __shfl_xor(m2j, msk);
      int oi = __shfl_xor(ij, msk);
      bool take = (o1 < m1j) || (o1 == m1j && oi < ij);
      float hi = take ? m1j : o1;  // losing min1 becomes min2 candidate
      m2j = fminf(fminf(m2j, o2), hi);
      m1j = take ? o1 : m1j;
      ij = take ? oi : ij;
    }
    if (col == 0) {
      s_idx[w * 16 + g * 4 + j] = ij;
      if (m2j - m1j < TAU) {
        int p = atomicAdd((int*)ctl, 1);
        wl[p] = r0 + g * 4 + j;
      }
    }
  }
  __syncthreads();

  // ---- fused output stage: 256 threads = 64 rows x 4 quarter-rows ----
  const int lr = threadIdx.x >> 2;       // local row 0..63
  const int q = threadIdx.x & 3;
  const int row = blockIdx.x * 64 + lr;
  const int code = s_idx[lr];
  const float4* zp4 = (const float4*)(z + (size_t)row * DIMS + q * 16);
  const float4* ep4 = (const float4*)(cb + (size_t)code * DIMS + q * 16);
  float4* op = (float4*)(out + (size_t)row * DIMS + q * 16);
  float sse = 0.f;
#pragma unroll
  for (int i = 0; i < 4; ++i) {
    float4 v = zp4[i], e = ep4[i];
    float dx = e.x - v.x, dy = e.y - v.y, dz = e.z - v.z, dw = e.w - v.w;
    sse = fmaf(dx, dx, sse);
    sse = fmaf(dy, dy, sse);
    sse = fmaf(dz, dz, sse);
    sse = fmaf(dw, dw, sse);
    float4 o;
    o.x = v.x + dx;
    o.y = v.y + dy;
    o.z = v.z + dz;
    o.w = v.w + dw;
    op[i] = o;
  }
  // quad-reduce (4 consecutive lanes = one row) then one write per row
  sse += __shfl_xor(sse, 1);
  sse += __shfl_xor(sse, 2);
  if (q == 0) srow[row] = sse;
}

// exact fp64 re-resolution for flagged rows; writes corrected out row + srow
__global__ __launch_bounds__(256) void k_refine(const float* __restrict__ z,
                                                const float* __restrict__ cb,
                                                const int* __restrict__ wl,
                                                const unsigned int* __restrict__ ctl,
                                                float* __restrict__ out,
                                                float* __restrict__ srow) {
  __shared__ float zz[64];
  __shared__ double sd[256];
  __shared__ int si[256];
  __shared__ float s_pf[16];
  const int t = threadIdx.x;
  const int n = (int)ctl[0];
  for (int wi = blockIdx.x; wi < n; wi += 1024) {
    const int row = wl[wi];
    if (t < 16) ((float4*)zz)[t] = ((const float4*)(z + (size_t)row * DIMS))[t];
    __syncthreads();
    const int c0 = t * 4;
    double accd[4] = {0.0, 0.0, 0.0, 0.0};
    for (int ch = 0; ch < 4; ++ch) {
      float zr[16];
#pragma unroll
      for (int q = 0; q < 4; ++q) ((float4*)zr)[q] = ((float4*)zz)[ch * 4 + q];
#pragma unroll
      for (int cc = 0; cc < 4; ++cc) {
        const float* e = cb + (size_t)(c0 + cc) * DIMS + ch * 16;
#pragma unroll
        for (int q = 0; q < 16; ++q) {
          double df = (double)zr[q] - (double)e[q];
          accd[cc] = fma(df, df, accd[cc]);
        }
      }
    }
    double best = 1e300;
    int bi = 0;
#pragma unroll
    for (int cc = 0; cc < 4; ++cc)
      if (accd[cc] < best) { best = accd[cc]; bi = c0 + cc; }
    sd[t] = best;
    si[t] = bi;
    __syncthreads();
    for (int off = 128; off > 0; off >>= 1) {
      if (t < off) {
        double ob = sd[t + off];
        int oi = si[t + off];
        if (ob < sd[t] || (ob == sd[t] && oi < si[t])) { sd[t] = ob; si[t] = oi; }
      }
      __syncthreads();
    }
    // corrected output + per-row sse for this row
    const int code = si[0];
    if (t < 16) {
      float4 v = ((const float4*)zz)[t];
      float4 e = ((const float4*)(cb + (size_t)code * DIMS))[t];
      float dx = e.x - v.x, dy = e.y - v.y, dz = e.z - v.z, dw = e.w - v.w;
      float s4 = dx * dx;
      s4 = fmaf(dy, dy, s4);
      s4 = fmaf(dz, dz, s4);
      s4 = fmaf(dw, dw, s4);
      s_pf[t] = s4;
      float4 o;
      o.x = v.x + dx;
      o.y = v.y + dy;
      o.z = v.z + dz;
      o.w = v.w + dw;
      ((float4*)(out + (size_t)row * DIMS))[t] = o;
    }
    __syncthreads();
    if (t == 0) {
      float s = 0.f;
#pragma unroll
      for (int i = 0; i < 16; ++i) s += s_pf[i];
      srow[row] = s;
    }
    __syncthreads();
  }
}

// deterministic loss: fixed-order sum of per-row sse
__global__ __launch_bounds__(1024) void k_loss(const float* __restrict__ srow,
                                               float* __restrict__ out) {
  __shared__ float sh[1024];
  const int t = threadIdx.x;
  float a0 = 0.f, a1 = 0.f, a2 = 0.f, a3 = 0.f;
#pragma unroll
  for (int i = 0; i < 16; ++i) {  // 64 values/thread, 4 chains
    a0 += srow[t + (4 * i + 0) * 1024];
    a1 += srow[t + (4 * i + 1) * 1024];
    a2 += srow[t + (4 * i + 2) * 1024];
    a3 += srow[t + (4 * i + 3) * 1024];
  }
  sh[t] = (a0 + a1) + (a2 + a3);
  __syncthreads();
  for (int off = 512; off > 0; off >>= 1) {
    if (t < off) sh[t] += sh[t + off];
    __syncthreads();
  }
  if (t == 0) {
    // (0.1*mse + mse) * 10 = 11 * SSE / (M*D)
    out[(size_t)M_TOTAL * DIMS] = sh[0] * (11.0f / (float)((size_t)M_TOTAL * DIMS));
  }
}

extern "C" void kernel_launch(void* const* d_in, const int* in_sizes, int n_in,
                              void* d_out, int out_size, void* d_ws, size_t ws_size,
                              hipStream_t stream) {
  const float* z = (const float*)d_in[0];
  const float* cb = (const float*)d_in[1];
  float* out = (float*)d_out;
  float* ws = (float*)d_ws;

  float* se = ws + SE_OFF;
  unsigned int* ctl = (unsigned int*)(ws + CTL_OFF);
  unsigned short* pbh = (unsigned short*)(ws + PBH_OFF);
  unsigned short* pbl = (unsigned short*)(ws + PBL_OFF);
  int* wl = (int*)(ws + WL_OFF);
  float* srow = ws + SROW_OFF;

  k_prep<<<32, 256, 0, stream>>>(cb, se, ctl, pbh, pbl);
  k_dist<<<M_TOTAL / 64, 256, 0, stream>>>(z, pbh, pbl, se, cb, out, srow, wl, ctl);
  k_refine<<<1024, 256, 0, stream>>>(z, cb, wl, ctl, out, srow);
  k_loss<<<1, 1024, 0, stream>>>(srow, out);
}

// Round 18
// 58.530 us; speedup vs baseline: 1.3806x; 1.0695x over previous
//
#include <hip/hip_runtime.h>
#include <hip/hip_bf16.h>
#include <float.h>

#define DIMS 64
#define KC 1024
#define M_TOTAL 65536
#define TAU 4e-3f   // split-bf16 dist err ~1.5e-4 std (proven r3-r17)

typedef __attribute__((ext_vector_type(8))) short bf16x8;   // 8 bf16 = 4 VGPRs
typedef __attribute__((ext_vector_type(4))) float f32x4;

// ---------------- ws layout (float elements), 200704 f = 803 KB -------------
#define SE_OFF   0            // 1024 f32 codebook sq norms
#define CTL_OFF  1024         // [0]=refine cnt
#define PART_OFF 2048         // 1024 f32 loss partials
#define PBH_OFF  4096         // 32768 f32: bf16 hi frags
#define PBL_OFF  36864        // 32768 f32: bf16 lo frags
#define IDX_OFF  69632        // 65536 int argmin per row
#define WL_OFF   135168       // 65536 int worklist (own region: k_dist writes it live)

// counted-wait + barrier fused in ONE asm (T3/T4): no vmcnt(0) drain in steady state.
// Placed at TOP of each iteration, BEFORE the reads; stage-issue goes AFTER the
// reads (bottom) so a buffer is only overwritten one full barrier after its last read.
#define WBAR(N) asm volatile("s_waitcnt vmcnt(" #N ")\n\ts_barrier" ::: "memory")

__device__ inline short f2bf(float x) {
  union { __hip_bfloat16 h; short s; } u;
  u.h = __float2bfloat16(x);
  return u.s;
}
__device__ inline float bf2f(short x) {
  union { short s; __hip_bfloat16 h; } u;
  u.s = x;
  return __bfloat162float(u.h);
}

// async global->LDS, 16B per lane; lds dest wave-uniform (HW writes dest + lane*16)
__device__ inline void gload_lds16(const void* g, void* l) {
  __builtin_amdgcn_global_load_lds(
      (const __attribute__((address_space(1))) void*)g,
      (__attribute__((address_space(3))) void*)l, 16, 0, 0);
}

// fused: pack codebook into bf16 MFMA B-fragment layout (hi + lo residue) + sq norms + zero ctl
// frag[((tile*2 + ks)*64 + lane)*8 + j] = E[16*tile + (lane&15)][32*ks + (lane>>4)*8 + j]
__global__ __launch_bounds__(256) void k_prep(const float* __restrict__ cb,
                                              float* __restrict__ se,
                                              unsigned int* __restrict__ ctl,
                                              unsigned short* __restrict__ pbh,
                                              unsigned short* __restrict__ pbl) {
  const int tid = blockIdx.x * 256 + threadIdx.x;  // 8192 total
  if (tid < 4) ctl[tid] = 0;
  const int l = tid & 63;
  const int s = (tid >> 6) & 1;
  const int tt = tid >> 7;
  const int code = tt * 16 + (l & 15);
  const int k = s * 32 + (l >> 4) * 8;
  const float* p = cb + (size_t)code * DIMS + k;
  float v[8];
  ((float4*)v)[0] = ((const float4*)p)[0];
  ((float4*)v)[1] = ((const float4*)p)[1];
  bf16x8 h, lo;
#pragma unroll
  for (int j = 0; j < 8; ++j) {
    short hj = f2bf(v[j]);
    h[j] = hj;
    lo[j] = f2bf(v[j] - bf2f(hj));
  }
  *(bf16x8*)(pbh + (size_t)tid * 8) = h;
  *(bf16x8*)(pbl + (size_t)tid * 8) = lo;

  if (tid < KC) {
    const float4* q = (const float4*)(cb + (size_t)tid * DIMS);
    float a0 = 0.f, a1 = 0.f, a2 = 0.f, a3 = 0.f;
#pragma unroll
    for (int i = 0; i < DIMS / 4; ++i) {
      float4 u = q[i];
      a0 = fmaf(u.x, u.x, a0);
      a1 = fmaf(u.y, u.y, a1);
      a2 = fmaf(u.z, u.z, a2);
      a3 = fmaf(u.w, u.w, a3);
    }
    se[tid] = (a0 + a1) + (a2 + a3);
  }
}

// load one A-row-piece as split bf16 of (-2*z): h + residual.
// hi(-2z) = -2*hi(z) exactly (pow2 scale) -> numerics match the proven form.
__device__ inline void loadA(const float* zp, bf16x8& h, bf16x8& lo) {
  float v[8];
  ((float4*)v)[0] = ((const float4*)zp)[0];
  ((float4*)v)[1] = ((const float4*)zp)[1];
#pragma unroll
  for (int j = 0; j < 8; ++j) {
    float s = -2.f * v[j];
    short hj = f2bf(s);
    h[j] = hj;
    lo[j] = f2bf(s - bf2f(hj));
  }
}

#define UPD(dv, m1v, m2v, btv)                        \
  {                                                   \
    float d_ = (dv);                                  \
    m2v = __builtin_amdgcn_fmed3f(d_, m1v, m2v);      \
    bool lt_ = d_ < m1v;                              \
    m1v = lt_ ? d_ : m1v;                             \
    btv = lt_ ? ct : btv;                             \
  }

// MFMA phase-1 (split bf16): wave = 16 rows x 1024 codes.
// Ring-3 LDS chunk buffers; schedule per iter: {vmcnt(2)+barrier -> read chunk c ->
// MFMA -> issue stage(c+2)}. Loads for chunk c+1 stay in flight across every barrier.
// C/D layout (m89-verified): col = lane&15, row = (lane>>4)*4 + reg.
__global__ __launch_bounds__(256, 4) void k_dist(const float* __restrict__ z,
                                                 const unsigned short* __restrict__ pbh,
                                                 const unsigned short* __restrict__ pbl,
                                                 const float* __restrict__ se,
                                                 int* __restrict__ idxo,
                                                 int* __restrict__ wl,
                                                 unsigned int* __restrict__ ctl) {
  __shared__ bf16x8 sB[3][2][256];  // ring of 3 chunk buffers (8 KB each) = 24 KB
  __shared__ float sSE[KC];         // 4 KB
  const int l = threadIdx.x & 63;
  const int w = threadIdx.x >> 6;
  const int r0 = blockIdx.x * 64 + w * 16;
  const int col = l & 15;
  const int g = l >> 4;

  // A loads first (oldest in the vmcnt FIFO: the compiler's wait for the
  // conversions then never forces the staging loads to drain)
  const float* zp = z + (size_t)(r0 + col) * DIMS + g * 8;
  bf16x8 ah0, ah1, al0, al1;
  loadA(zp, ah0, al0);
  loadA(zp + 32, ah1, al1);

  // prologue staging: se (1 gload/wave) + chunks 0,1 (2 gloads/wave each)
  gload_lds16(se + w * 256 + l * 4, &sSE[w * 256]);
  {
    const size_t f0 = (size_t)w * 64 + l;
    gload_lds16(pbh + f0 * 8, &sB[0][0][w * 64]);
    gload_lds16(pbl + f0 * 8, &sB[0][1][w * 64]);
    const size_t f1 = 256 + (size_t)w * 64 + l;
    gload_lds16(pbh + f1 * 8, &sB[1][0][w * 64]);
    gload_lds16(pbl + f1 * 8, &sB[1][1][w * 64]);
  }

  float m10 = FLT_MAX, m11 = FLT_MAX, m12 = FLT_MAX, m13 = FLT_MAX;
  float m20 = FLT_MAX, m21 = FLT_MAX, m22 = FLT_MAX, m23 = FLT_MAX;
  int bt0 = 0, bt1 = 0, bt2 = 0, bt3 = 0;

  int bufc = 0;  // ring buffer holding chunk c
  for (int c = 0; c < 32; ++c) {  // 32 chunks x 32 codes
    // top-of-iter wait: outstanding = chunks c, c+1 (4 loads) -> vmcnt(2) leaves
    // only chunk c+1 in flight => chunk c (and se at c=0) resident. Drain at c=31.
    if (c == 31) {
      WBAR(0);
    } else {
      WBAR(2);
    }
#pragma unroll
    for (int tt = 0; tt < 2; ++tt) {
      const int ct = c * 2 + tt;  // global 16-code tile index [0,64)
      bf16x8 bh0 = sB[bufc][0][tt * 128 + l];
      bf16x8 bh1 = sB[bufc][0][tt * 128 + 64 + l];
      bf16x8 bl0 = sB[bufc][1][tt * 128 + l];
      bf16x8 bl1 = sB[bufc][1][tt * 128 + 64 + l];
      const float sec = sSE[ct * 16 + col];
      f32x4 acc = {sec, sec, sec, sec};  // d = se + (-2z).e : no epilogue fma
      __builtin_amdgcn_s_setprio(1);
      acc = __builtin_amdgcn_mfma_f32_16x16x32_bf16(ah0, bh0, acc, 0, 0, 0);
      acc = __builtin_amdgcn_mfma_f32_16x16x32_bf16(ah1, bh1, acc, 0, 0, 0);
      acc = __builtin_amdgcn_mfma_f32_16x16x32_bf16(ah0, bl0, acc, 0, 0, 0);
      acc = __builtin_amdgcn_mfma_f32_16x16x32_bf16(ah1, bl1, acc, 0, 0, 0);
      acc = __builtin_amdgcn_mfma_f32_16x16x32_bf16(al0, bh0, acc, 0, 0, 0);
      acc = __builtin_amdgcn_mfma_f32_16x16x32_bf16(al1, bh1, acc, 0, 0, 0);
      __builtin_amdgcn_s_setprio(0);
      UPD(acc[0], m10, m20, bt0);
      UPD(acc[1], m11, m21, bt1);
      UPD(acc[2], m12, m22, bt2);
      UPD(acc[3], m13, m23, bt3);
    }
    // bottom-of-iter stage: chunk c+2 into buffer (c+2)%3, which held chunk c-1;
    // all reads of chunk c-1 completed before this iteration's barrier -> race-free.
    if (c < 30) {
      int nb = bufc + 2;
      if (nb >= 3) nb -= 3;
      const size_t f = (size_t)(c + 2) * 256 + w * 64 + l;
      gload_lds16(pbh + f * 8, &sB[nb][0][w * 64]);
      gload_lds16(pbl + f * 8, &sB[nb][1][w * 64]);
    }
    bufc++;
    if (bufc == 3) bufc = 0;
  }

  // cross-lane reduce over the 16 cols of each row group; lowest-index tie-break
  float m1s[4] = {m10, m11, m12, m13};
  float m2s[4] = {m20, m21, m22, m23};
  int bts[4] = {bt0, bt1, bt2, bt3};
#pragma unroll
  for (int j = 0; j < 4; ++j) {
    float m1j = m1s[j], m2j = m2s[j];
    int ij = bts[j] * 16 + col;  // global code index
    for (int msk = 1; msk <= 8; msk <<= 1) {
      float o1 = __shfl_xor(m1j, msk);
      float o2 = __shfl_xor(m2j, msk);
      int oi = __shfl_xor(ij, msk);
      bool take = (o1 < m1j) || (o1 == m1j && oi < ij);
      float hi = take ? m1j : o1;  // losing min1 becomes min2 candidate
      m2j = fminf(fminf(m2j, o2), hi);
      m1j = take ? o1 : m1j;
      ij = take ? oi : ij;
    }
    if (col == 0) {
      const int row = r0 + g * 4 + j;
      idxo[row] = ij;
      if (m2j - m1j < TAU) {
        int p = atomicAdd((int*)ctl, 1);
        wl[p] = row;
      }
    }
  }
}

// exact fp64 diff-form re-resolution for flagged rows (worklist, ~0.3% of rows)
__global__ __launch_bounds__(256) void k_refine(const float* __restrict__ z,
                                                const float* __restrict__ cb,
                                                const int* __restrict__ wl,
                                                const unsigned int* __restrict__ ctl,
                                                int* __restrict__ idxo) {
  __shared__ float zz[64];
  __shared__ double sd[256];
  __shared__ int si[256];
  const int t = threadIdx.x;
  const int n = (int)ctl[0];
  for (int wi = blockIdx.x; wi < n; wi += 512) {
    const int row = wl[wi];
    if (t < 16) ((float4*)zz)[t] = ((const float4*)(z + (size_t)row * DIMS))[t];
    __syncthreads();
    const int c0 = t * 4;
    double accd[4] = {0.0, 0.0, 0.0, 0.0};
    for (int ch = 0; ch < 4; ++ch) {
      float zr[16];
#pragma unroll
      for (int q = 0; q < 4; ++q) ((float4*)zr)[q] = ((float4*)zz)[ch * 4 + q];
#pragma unroll
      for (int cc = 0; cc < 4; ++cc) {
        const float* e = cb + (size_t)(c0 + cc) * DIMS + ch * 16;
#pragma unroll
        for (int q = 0; q < 16; ++q) {
          double df = (double)zr[q] - (double)e[q];
          accd[cc] = fma(df, df, accd[cc]);
        }
      }
    }
    double best = 1e300;
    int bi = 0;
#pragma unroll
    for (int cc = 0; cc < 4; ++cc)
      if (accd[cc] < best) { best = accd[cc]; bi = c0 + cc; }
    sd[t] = best;
    si[t] = bi;
    __syncthreads();
    for (int off = 128; off > 0; off >>= 1) {
      if (t < off) {
        double ob = sd[t + off];
        int oi = si[t + off];
        if (ob < sd[t] || (ob == sd[t] && oi < si[t])) { sd[t] = ob; si[t] = oi; }
      }
      __syncthreads();
    }
    if (t == 0) idxo[row] = si[0];
    __syncthreads();
  }
}

// gather + straight-through output (z + (e - z), ref rounding) + loss partials
__global__ __launch_bounds__(256) void k_out(const float* __restrict__ z,
                                             const float* __restrict__ cb,
                                             const int* __restrict__ idxi,
                                             float* __restrict__ out,
                                             float* __restrict__ partials) {
  const int tid = blockIdx.x * 256 + threadIdx.x;  // 262144: quarter-row each
  const int row = tid >> 2;
  const int q = tid & 3;
  const int code = idxi[row];
  const float4* zp = (const float4*)(z + (size_t)row * DIMS + q * 16);
  const float4* ep = (const float4*)(cb + (size_t)code * DIMS + q * 16);
  float4* op = (float4*)(out + (size_t)row * DIMS + q * 16);
  float sse = 0.f;
#pragma unroll
  for (int i = 0; i < 4; ++i) {
    float4 v = zp[i], e = ep[i];
    float dx = e.x - v.x, dy = e.y - v.y, dz = e.z - v.z, dw = e.w - v.w;
    sse = fmaf(dx, dx, sse);
    sse = fmaf(dy, dy, sse);
    sse = fmaf(dz, dz, sse);
    sse = fmaf(dw, dw, sse);
    float4 o;
    o.x = v.x + dx;
    o.y = v.y + dy;
    o.z = v.z + dz;
    o.w = v.w + dw;
    op[i] = o;
  }
  __shared__ float sh[256];
  sh[threadIdx.x] = sse;
  __syncthreads();
  for (int off = 128; off > 0; off >>= 1) {
    if (threadIdx.x < off) sh[threadIdx.x] += sh[threadIdx.x + off];
    __syncthreads();
  }
  if (threadIdx.x == 0) partials[blockIdx.x] = sh[0];
}

__global__ __launch_bounds__(256) void k_loss(const float* __restrict__ partials,
                                              float* __restrict__ out) {
  __shared__ float sh[256];
  const int t = threadIdx.x;
  sh[t] = partials[t] + partials[t + 256] + partials[t + 512] + partials[t + 768];
  __syncthreads();
  for (int off = 128; off > 0; off >>= 1) {
    if (t < off) sh[t] += sh[t + off];
    __syncthreads();
  }
  if (t == 0) {
    // (0.1*mse + mse) * 10 = 11 * SSE / (M*D)
    out[(size_t)M_TOTAL * DIMS] = sh[0] * (11.0f / (float)((size_t)M_TOTAL * DIMS));
  }
}

extern "C" void kernel_launch(void* const* d_in, const int* in_sizes, int n_in,
                              void* d_out, int out_size, void* d_ws, size_t ws_size,
                              hipStream_t stream) {
  const float* z = (const float*)d_in[0];
  const float* cb = (const float*)d_in[1];
  float* out = (float*)d_out;
  float* ws = (float*)d_ws;

  float* se = ws + SE_OFF;
  unsigned int* ctl = (unsigned int*)(ws + CTL_OFF);
  float* partials = ws + PART_OFF;
  unsigned short* pbh = (unsigned short*)(ws + PBH_OFF);
  unsigned short* pbl = (unsigned short*)(ws + PBL_OFF);
  int* idx = (int*)(ws + IDX_OFF);
  int* wl = (int*)(ws + WL_OFF);

  k_prep<<<32, 256, 0, stream>>>(cb, se, ctl, pbh, pbl);
  k_dist<<<M_TOTAL / 64, 256, 0, stream>>>(z, pbh, pbl, se, idx, wl, ctl);
  k_refine<<<512, 256, 0, stream>>>(z, cb, wl, ctl, idx);
  k_out<<<M_TOTAL / 64, 256, 0, stream>>>(z, cb, idx, out, partials);
  k_loss<<<1, 256, 0, stream>>>(partials, out);
}